// Round 18
// baseline (14.201 us; speedup 1.0000x reference)
//
#include <hip/hip_runtime.h>
#include <hip/hip_bf16.h>
#include <float.h>

#define N_LOC 101
#define TAUC 0.5f
#define RAC  0.5f
#define EPSV 1e-4f

__device__ __forceinline__ float wsum64(float v) {
    #pragma unroll
    for (int off = 32; off; off >>= 1) v += __shfl_xor(v, off);
    return v;
}

__device__ __forceinline__ void fma4(float* acc, float s, float4 v) {
    acc[0] += s * v.x; acc[1] += s * v.y;
    acc[2] += s * v.z; acc[3] += s * v.w;
}

// ---------------------------------------------------------------------------
// fused4x v2 — DS-cut bundle on the verified round-17 structure:
//  * no xs staging: phase 1 reads x from global (broadcast, L2-hot)
//  * reduce steps spread over all 256 threads (float2 each)
//  * phase-3 h2 reads as 4 x b128
// grid = B/4 = 1024, 256 threads, 4 blocks/CU (16 waves/CU).
// ---------------------------------------------------------------------------
__global__ __launch_bounds__(256, 4) void fused4x_kernel(
    const float* __restrict__ x,
    const float* __restrict__ p0, const float* __restrict__ p1,
    const float* __restrict__ p2, const float* __restrict__ p3,
    const float* __restrict__ p4, const float* __restrict__ p5,
    const float* __restrict__ p6, const float* __restrict__ p7,
    const float* __restrict__ W1, const float* __restrict__ b1,
    const float* __restrict__ W2, const float* __restrict__ b2,
    const float* __restrict__ W3, const float* __restrict__ b3,
    float* __restrict__ out_pdf, float* __restrict__ out_z,
    float* __restrict__ out_err, int B)
{
    __shared__ float hp [8][4 * 128];   // 16 KB K-split partials
    __shared__ float h1s[4 * 128];      // 2 KB
    __shared__ float h2s[4 * 128];      // 2 KB

    const int t   = threadIdx.x;
    const int r0b = blockIdx.x * 4;

    const int jg = t & 31;
    const int j0 = jg * 4;
    const int kh = t >> 5;              // 0..7 K-chunk

    // ---- phase 1: h1 = relu(x @ W1 + b1), K=64, 8 kk per chunk, M_r=4
    // x read directly from global (same addr for 32 lanes -> broadcast).
    {
        float acc[4][4] = {};
        const int kb = kh * 8;
        #pragma unroll
        for (int kq = 0; kq < 8; kq += 4) {
            float4 w[4];
            #pragma unroll
            for (int q = 0; q < 4; ++q)
                w[q] = *reinterpret_cast<const float4*>(&W1[(kb + kq + q) * 128 + j0]);
            #pragma unroll
            for (int r = 0; r < 4; ++r) {
                const float4 xv = *reinterpret_cast<const float4*>(&x[(r0b + r) * 64 + kb + kq]);
                fma4(acc[r], xv.x, w[0]);
                fma4(acc[r], xv.y, w[1]);
                fma4(acc[r], xv.z, w[2]);
                fma4(acc[r], xv.w, w[3]);
            }
        }
        #pragma unroll
        for (int r = 0; r < 4; ++r) {
            float4 o; o.x = acc[r][0]; o.y = acc[r][1]; o.z = acc[r][2]; o.w = acc[r][3];
            *reinterpret_cast<float4*>(&hp[kh][r * 128 + j0]) = o;
        }
    }
    __syncthreads();
    {   // reduce 8 partials + bias + relu -> h1s (float2 per thread, all 256)
        const int idx = t * 2;          // 0..510
        const int r   = idx >> 7;
        const int jj  = idx & 127;
        float2 a = *reinterpret_cast<const float2*>(&b1[jj]);
        #pragma unroll
        for (int k2 = 0; k2 < 8; ++k2) {
            const float2 q = *reinterpret_cast<const float2*>(&hp[k2][r * 128 + jj]);
            a.x += q.x; a.y += q.y;
        }
        float2 o;
        o.x = fmaxf(a.x, 0.f); o.y = fmaxf(a.y, 0.f);
        *reinterpret_cast<float2*>(&h1s[r * 128 + jj]) = o;
    }
    __syncthreads();

    // ---- phase 2: h2 = relu(h1 @ W2 + b2), K=128, 16 kk per chunk, M_r=4
    {
        float acc[4][4] = {};
        const int kb = kh * 16;
        #pragma unroll
        for (int kq = 0; kq < 16; kq += 4) {
            float4 w[4];
            #pragma unroll
            for (int q = 0; q < 4; ++q)
                w[q] = *reinterpret_cast<const float4*>(&W2[(kb + kq + q) * 128 + j0]);
            #pragma unroll
            for (int r = 0; r < 4; ++r) {
                const float4 hv = *reinterpret_cast<const float4*>(&h1s[r * 128 + kb + kq]);
                fma4(acc[r], hv.x, w[0]);
                fma4(acc[r], hv.y, w[1]);
                fma4(acc[r], hv.z, w[2]);
                fma4(acc[r], hv.w, w[3]);
            }
        }
        #pragma unroll
        for (int r = 0; r < 4; ++r) {
            float4 o; o.x = acc[r][0]; o.y = acc[r][1]; o.z = acc[r][2]; o.w = acc[r][3];
            *reinterpret_cast<float4*>(&hp[kh][r * 128 + j0]) = o;
        }
    }
    __syncthreads();
    {   // reduce + bias + relu -> h2s (float2 per thread, all 256)
        const int idx = t * 2;
        const int r   = idx >> 7;
        const int jj  = idx & 127;
        float2 a = *reinterpret_cast<const float2*>(&b2[jj]);
        #pragma unroll
        for (int k2 = 0; k2 < 8; ++k2) {
            const float2 q = *reinterpret_cast<const float2*>(&hp[k2][r * 128 + jj]);
            a.x += q.x; a.y += q.y;
        }
        float2 o;
        o.x = fmaxf(a.x, 0.f); o.y = fmaxf(a.y, 0.f);
        *reinterpret_cast<float2*>(&h2s[r * 128 + jj]) = o;
    }
    __syncthreads();

    // ---- per-wave: row = r0b + wid: phase 3 + softmax + solve
    const int wid  = t >> 6;
    const int lane = t & 63;
    const int e    = lane & 7;
    const int kc   = lane >> 3;
    const int n1 = lane, n2 = lane + 64;
    const bool v2 = (n2 < N_LOC);
    const float s1 = n1 * 0.01f, s2 = n2 * 0.01f;

    const int row = r0b + wid;

    // phase 3: logits via (e, kc) decomposition; h2 as 4 x b128
    float hreg[16];
    #pragma unroll
    for (int q4 = 0; q4 < 4; ++q4) {
        const float4 h4 = *reinterpret_cast<const float4*>(&h2s[wid * 128 + kc * 16 + q4 * 4]);
        hreg[q4*4+0] = h4.x; hreg[q4*4+1] = h4.y;
        hreg[q4*4+2] = h4.z; hreg[q4*4+3] = h4.w;
    }
    float acc3 = 0.f;
    #pragma unroll
    for (int i = 0; i < 16; ++i)
        acc3 += hreg[i] * W3[(kc * 16 + i) * 8 + e];
    acc3 += __shfl_xor(acc3, 8);
    acc3 += __shfl_xor(acc3, 16);
    acc3 += __shfl_xor(acc3, 32);
    const float logit = acc3 + b3[e];
    float m = logit;
    m = fmaxf(m, __shfl_xor(m, 1));
    m = fmaxf(m, __shfl_xor(m, 2));
    m = fmaxf(m, __shfl_xor(m, 4));
    const float ex = expf(logit - m);
    float s = ex;
    s += __shfl_xor(s, 1);
    s += __shfl_xor(s, 2);
    s += __shfl_xor(s, 4);
    const float wgt = ex / s;

    float wv8[8];
    #pragma unroll
    for (int e2 = 0; e2 < 8; ++e2) wv8[e2] = __shfl(wgt, e2);

    // combined pdf
    const long base = (long)row * N_LOC;
    float pdf1, pdf2;
    {
        const float* pp[8] = { p0+base, p1+base, p2+base, p3+base,
                               p4+base, p5+base, p6+base, p7+base };
        pdf1 = 0.f; pdf2 = 0.f;
        #pragma unroll
        for (int ee = 0; ee < 8; ++ee) {
            pdf1 += wv8[ee] * pp[ee][n1];
            pdf2 += wv8[ee] * (v2 ? pp[ee][n2] : 0.f);
        }
    }
    out_pdf[base + n1] = pdf1;
    if (v2) out_pdf[base + n2] = pdf2;

    // ---- convex-crossing solve (verified round-16)
    float ap = pdf1, bp = pdf2;
    #pragma unroll
    for (int off = 1; off < 64; off <<= 1) {
        float t0 = __shfl_up(ap, off);
        float t1 = __shfl_up(bp, off);
        if (lane >= off) { ap += t0; bp += t1; }
    }
    const float TaP = __shfl(ap, 63);
    const float TbP = __shfl(bp, 63);
    const float P   = TaP + TbP;
    const float Sp  = wsum64(pdf1*s1 + pdf2*s2);
    const float Q   = P  + (float)N_LOC * EPSV;
    const float Sq  = Sp + 50.5f * EPSV;

    float eC1 = __shfl_up(ap, 1); if (lane == 0) eC1 = 0.f;
    float eC2 = __shfl_up(bp, 1); if (lane == 0) eC2 = 0.f;
    eC2 += TaP;

    // z_unc(C) = (Sq + 0.25P - 0.5C)/Q  (TAU=RA=1/2 closed form)
    const float zu1 = (Sq + 0.25f * P - 0.5f * eC1) / Q;
    const float zu2 = (Sq + 0.25f * P - 0.5f * eC2) / Q;
    const float lo1 = (n1 == 0) ? 0.f : (n1 - 1) * 0.01f;
    const float hi1 = n1 * 0.01f;
    const float lo2 = (n2 - 1) * 0.01f;
    const float hi2 = n2 * 0.01f;

    const unsigned long long m1 = __ballot(zu1 >= lo1);         // lane0 always set
    const unsigned long long m2 = __ballot(v2 && (zu2 >= lo2));

    int kstar;
    if (m2) kstar = 64 + (63 - __builtin_clzll(m2));
    else    kstar = 63 - __builtin_clzll(m1);

    const float z1c = fminf(fmaxf(zu1, lo1), hi1);
    const float z2c = fminf(fmaxf(zu2, lo2), hi2);
    const int   kl  = (kstar >= 64) ? (kstar - 64) : kstar;
    const float bz  = __shfl((kstar >= 64) ? z2c : z1c, kl);

    if (lane == 0) out_z[row] = bz;
    out_err[base + n1] = s1 - bz;
    if (v2) out_err[base + n2] = s2 - bz;
}

extern "C" void kernel_launch(void* const* d_in, const int* in_sizes, int n_in,
                              void* d_out, int out_size, void* d_ws, size_t ws_size,
                              hipStream_t stream)
{
    const float* x  = (const float*)d_in[0];
    const float* p[8];
    for (int e = 0; e < 8; ++e) p[e] = (const float*)d_in[1 + e];
    const float* W1 = (const float*)d_in[9];
    const float* b1 = (const float*)d_in[10];
    const float* W2 = (const float*)d_in[11];
    const float* b2 = (const float*)d_in[12];
    const float* W3 = (const float*)d_in[13];
    const float* b3 = (const float*)d_in[14];

    const int B = in_sizes[0] / 64;         // 4096
    float* out_pdf = (float*)d_out;         // [B][101]
    float* out_z   = out_pdf + (size_t)B * N_LOC;   // [B]
    float* out_err = out_z + B;             // [B][101]

    fused4x_kernel<<<B / 4, 256, 0, stream>>>(
        x, p[0], p[1], p[2], p[3], p[4], p[5], p[6], p[7],
        W1, b1, W2, b2, W3, b3, out_pdf, out_z, out_err, B);
}

// Round 19
// 13.504 us; speedup vs baseline: 1.0516x; 1.0516x over previous
//
#include <hip/hip_runtime.h>
#include <hip/hip_bf16.h>
#include <float.h>

#define N_LOC 101
#define TAUC 0.5f
#define RAC  0.5f
#define EPSV 1e-4f

__device__ __forceinline__ float wsum64(float v) {
    #pragma unroll
    for (int off = 32; off; off >>= 1) v += __shfl_xor(v, off);
    return v;
}

__device__ __forceinline__ void fma4(float* acc, float s, float4 v) {
    acc[0] += s * v.x; acc[1] += s * v.y;
    acc[2] += s * v.z; acc[3] += s * v.w;
}

// ---------------------------------------------------------------------------
// fused4x v3 — R17 verified structure (xs staged in LDS, 13.60us) plus ONLY
// the two safe pieces of R18's bundle:
//  (a) reduce steps spread over all 256 threads (float2 each)
//  (b) phase-3 h2 reads as 4 x b128
// The harmful piece (x read from global in phase 1) is REVERTED.
// grid = B/4 = 1024, 256 threads, 4 blocks/CU (16 waves/CU).
// ---------------------------------------------------------------------------
__global__ __launch_bounds__(256, 4) void fused4x_kernel(
    const float* __restrict__ x,
    const float* __restrict__ p0, const float* __restrict__ p1,
    const float* __restrict__ p2, const float* __restrict__ p3,
    const float* __restrict__ p4, const float* __restrict__ p5,
    const float* __restrict__ p6, const float* __restrict__ p7,
    const float* __restrict__ W1, const float* __restrict__ b1,
    const float* __restrict__ W2, const float* __restrict__ b2,
    const float* __restrict__ W3, const float* __restrict__ b3,
    float* __restrict__ out_pdf, float* __restrict__ out_z,
    float* __restrict__ out_err, int B)
{
    __shared__ float xs [4 * 64];       // 1 KB (staged x tile — R17 path)
    __shared__ float hp [8][4 * 128];   // 16 KB K-split partials
    __shared__ float h1s[4 * 128];      // 2 KB
    __shared__ float h2s[4 * 128];      // 2 KB

    const int t   = threadIdx.x;
    const int r0b = blockIdx.x * 4;

    // ---- stage x tile (4 x 64 = 256 floats)
    if (t < 64)
        *reinterpret_cast<float4*>(&xs[t * 4]) =
            *reinterpret_cast<const float4*>(&x[r0b * 64 + t * 4]);
    __syncthreads();

    const int jg = t & 31;
    const int j0 = jg * 4;
    const int kh = t >> 5;              // 0..7 K-chunk

    // ---- phase 1: h1 = relu(x @ W1 + b1), K=64, 8 kk per chunk, M_r=4
    {
        float acc[4][4] = {};
        const int kb = kh * 8;
        #pragma unroll
        for (int kq = 0; kq < 8; kq += 4) {
            float4 w[4];
            #pragma unroll
            for (int q = 0; q < 4; ++q)
                w[q] = *reinterpret_cast<const float4*>(&W1[(kb + kq + q) * 128 + j0]);
            #pragma unroll
            for (int r = 0; r < 4; ++r) {
                const float4 xv = *reinterpret_cast<const float4*>(&xs[r * 64 + kb + kq]);
                fma4(acc[r], xv.x, w[0]);
                fma4(acc[r], xv.y, w[1]);
                fma4(acc[r], xv.z, w[2]);
                fma4(acc[r], xv.w, w[3]);
            }
        }
        #pragma unroll
        for (int r = 0; r < 4; ++r) {
            float4 o; o.x = acc[r][0]; o.y = acc[r][1]; o.z = acc[r][2]; o.w = acc[r][3];
            *reinterpret_cast<float4*>(&hp[kh][r * 128 + j0]) = o;
        }
    }
    __syncthreads();
    {   // reduce 8 partials + bias + relu -> h1s (float2 per thread, all 256)
        const int idx = t * 2;          // 0..510
        const int r   = idx >> 7;
        const int jj  = idx & 127;
        float2 a = *reinterpret_cast<const float2*>(&b1[jj]);
        #pragma unroll
        for (int k2 = 0; k2 < 8; ++k2) {
            const float2 q = *reinterpret_cast<const float2*>(&hp[k2][r * 128 + jj]);
            a.x += q.x; a.y += q.y;
        }
        float2 o;
        o.x = fmaxf(a.x, 0.f); o.y = fmaxf(a.y, 0.f);
        *reinterpret_cast<float2*>(&h1s[r * 128 + jj]) = o;
    }
    __syncthreads();

    // ---- phase 2: h2 = relu(h1 @ W2 + b2), K=128, 16 kk per chunk, M_r=4
    {
        float acc[4][4] = {};
        const int kb = kh * 16;
        #pragma unroll
        for (int kq = 0; kq < 16; kq += 4) {
            float4 w[4];
            #pragma unroll
            for (int q = 0; q < 4; ++q)
                w[q] = *reinterpret_cast<const float4*>(&W2[(kb + kq + q) * 128 + j0]);
            #pragma unroll
            for (int r = 0; r < 4; ++r) {
                const float4 hv = *reinterpret_cast<const float4*>(&h1s[r * 128 + kb + kq]);
                fma4(acc[r], hv.x, w[0]);
                fma4(acc[r], hv.y, w[1]);
                fma4(acc[r], hv.z, w[2]);
                fma4(acc[r], hv.w, w[3]);
            }
        }
        #pragma unroll
        for (int r = 0; r < 4; ++r) {
            float4 o; o.x = acc[r][0]; o.y = acc[r][1]; o.z = acc[r][2]; o.w = acc[r][3];
            *reinterpret_cast<float4*>(&hp[kh][r * 128 + j0]) = o;
        }
    }
    __syncthreads();
    {   // reduce + bias + relu -> h2s (float2 per thread, all 256)
        const int idx = t * 2;
        const int r   = idx >> 7;
        const int jj  = idx & 127;
        float2 a = *reinterpret_cast<const float2*>(&b2[jj]);
        #pragma unroll
        for (int k2 = 0; k2 < 8; ++k2) {
            const float2 q = *reinterpret_cast<const float2*>(&hp[k2][r * 128 + jj]);
            a.x += q.x; a.y += q.y;
        }
        float2 o;
        o.x = fmaxf(a.x, 0.f); o.y = fmaxf(a.y, 0.f);
        *reinterpret_cast<float2*>(&h2s[r * 128 + jj]) = o;
    }
    __syncthreads();

    // ---- per-wave: row = r0b + wid: phase 3 + softmax + solve
    const int wid  = t >> 6;
    const int lane = t & 63;
    const int e    = lane & 7;
    const int kc   = lane >> 3;
    const int n1 = lane, n2 = lane + 64;
    const bool v2 = (n2 < N_LOC);
    const float s1 = n1 * 0.01f, s2 = n2 * 0.01f;

    const int row = r0b + wid;

    // phase 3: logits via (e, kc) decomposition; h2 as 4 x b128
    float hreg[16];
    #pragma unroll
    for (int q4 = 0; q4 < 4; ++q4) {
        const float4 h4 = *reinterpret_cast<const float4*>(&h2s[wid * 128 + kc * 16 + q4 * 4]);
        hreg[q4*4+0] = h4.x; hreg[q4*4+1] = h4.y;
        hreg[q4*4+2] = h4.z; hreg[q4*4+3] = h4.w;
    }
    float acc3 = 0.f;
    #pragma unroll
    for (int i = 0; i < 16; ++i)
        acc3 += hreg[i] * W3[(kc * 16 + i) * 8 + e];
    acc3 += __shfl_xor(acc3, 8);
    acc3 += __shfl_xor(acc3, 16);
    acc3 += __shfl_xor(acc3, 32);
    const float logit = acc3 + b3[e];
    float m = logit;
    m = fmaxf(m, __shfl_xor(m, 1));
    m = fmaxf(m, __shfl_xor(m, 2));
    m = fmaxf(m, __shfl_xor(m, 4));
    const float ex = expf(logit - m);
    float s = ex;
    s += __shfl_xor(s, 1);
    s += __shfl_xor(s, 2);
    s += __shfl_xor(s, 4);
    const float wgt = ex / s;

    float wv8[8];
    #pragma unroll
    for (int e2 = 0; e2 < 8; ++e2) wv8[e2] = __shfl(wgt, e2);

    // combined pdf
    const long base = (long)row * N_LOC;
    float pdf1, pdf2;
    {
        const float* pp[8] = { p0+base, p1+base, p2+base, p3+base,
                               p4+base, p5+base, p6+base, p7+base };
        pdf1 = 0.f; pdf2 = 0.f;
        #pragma unroll
        for (int ee = 0; ee < 8; ++ee) {
            pdf1 += wv8[ee] * pp[ee][n1];
            pdf2 += wv8[ee] * (v2 ? pp[ee][n2] : 0.f);
        }
    }
    out_pdf[base + n1] = pdf1;
    if (v2) out_pdf[base + n2] = pdf2;

    // ---- convex-crossing solve (verified round-16)
    float ap = pdf1, bp = pdf2;
    #pragma unroll
    for (int off = 1; off < 64; off <<= 1) {
        float t0 = __shfl_up(ap, off);
        float t1 = __shfl_up(bp, off);
        if (lane >= off) { ap += t0; bp += t1; }
    }
    const float TaP = __shfl(ap, 63);
    const float TbP = __shfl(bp, 63);
    const float P   = TaP + TbP;
    const float Sp  = wsum64(pdf1*s1 + pdf2*s2);
    const float Q   = P  + (float)N_LOC * EPSV;
    const float Sq  = Sp + 50.5f * EPSV;

    float eC1 = __shfl_up(ap, 1); if (lane == 0) eC1 = 0.f;
    float eC2 = __shfl_up(bp, 1); if (lane == 0) eC2 = 0.f;
    eC2 += TaP;

    // z_unc(C) = (Sq + 0.25P - 0.5C)/Q  (TAU=RA=1/2 closed form)
    const float zu1 = (Sq + 0.25f * P - 0.5f * eC1) / Q;
    const float zu2 = (Sq + 0.25f * P - 0.5f * eC2) / Q;
    const float lo1 = (n1 == 0) ? 0.f : (n1 - 1) * 0.01f;
    const float hi1 = n1 * 0.01f;
    const float lo2 = (n2 - 1) * 0.01f;
    const float hi2 = n2 * 0.01f;

    const unsigned long long m1 = __ballot(zu1 >= lo1);         // lane0 always set
    const unsigned long long m2 = __ballot(v2 && (zu2 >= lo2));

    int kstar;
    if (m2) kstar = 64 + (63 - __builtin_clzll(m2));
    else    kstar = 63 - __builtin_clzll(m1);

    const float z1c = fminf(fmaxf(zu1, lo1), hi1);
    const float z2c = fminf(fmaxf(zu2, lo2), hi2);
    const int   kl  = (kstar >= 64) ? (kstar - 64) : kstar;
    const float bz  = __shfl((kstar >= 64) ? z2c : z1c, kl);

    if (lane == 0) out_z[row] = bz;
    out_err[base + n1] = s1 - bz;
    if (v2) out_err[base + n2] = s2 - bz;
}

extern "C" void kernel_launch(void* const* d_in, const int* in_sizes, int n_in,
                              void* d_out, int out_size, void* d_ws, size_t ws_size,
                              hipStream_t stream)
{
    const float* x  = (const float*)d_in[0];
    const float* p[8];
    for (int e = 0; e < 8; ++e) p[e] = (const float*)d_in[1 + e];
    const float* W1 = (const float*)d_in[9];
    const float* b1 = (const float*)d_in[10];
    const float* W2 = (const float*)d_in[11];
    const float* b2 = (const float*)d_in[12];
    const float* W3 = (const float*)d_in[13];
    const float* b3 = (const float*)d_in[14];

    const int B = in_sizes[0] / 64;         // 4096
    float* out_pdf = (float*)d_out;         // [B][101]
    float* out_z   = out_pdf + (size_t)B * N_LOC;   // [B]
    float* out_err = out_z + B;             // [B][101]

    fused4x_kernel<<<B / 4, 256, 0, stream>>>(
        x, p[0], p[1], p[2], p[3], p[4], p[5], p[6], p[7],
        W1, b1, W2, b2, W3, b3, out_pdf, out_z, out_err, B);
}